// Round 5
// baseline (409.603 us; speedup 1.0000x reference)
//
#include <hip/hip_runtime.h>
#include <math.h>

#define NB 16
#define NN 16384
#define DD 128
#define KK 10

// ws layout (floats):
//   hsum : [2][NB][DD]      @0      4096   (plane 0 = sum over H1 rows, plane 1 = H2)
//   v    : [2][NB][KK][DD]  @4096   40960  (scale folded in: 1/(N*sqrt(d)))
//   accg : [2][NB][40]      @45056  1280   ([k]=SE, [10+k]=Yx, [20+k]=Yy, [30+k]=Yz)
#define WS_FLOATS 46336

// Geometry: 1024 blocks = 16 batches x 64 blocks; each block owns 256
// contiguous rows = 8 tiles of 32 rows (16 KB). Tiles are staged into LDS via
// global_load_lds DMA (no VGPR destination -> queue depth decoupled from the
// register allocator, which was capping us at ~2 outstanding loads/wave and
// ~1.5-2.6 TB/s effective read BW in rounds 1-4).
#define TROWS 32
#define TBYTES (TROWS * DD * 4)      // 16384
#define NTILES 8
#define RPB 256                      // rows per block

typedef __attribute__((address_space(1))) const void* as1cv;
typedef __attribute__((address_space(3))) void* as3v;

// Stage one 16-KB tile: wave w copies bytes [w*4K, w*4K+4K) in 4 x 1-KB DMAs.
// LDS dst must be wave-uniform base; lane i lands at base + i*16 (linear).
__device__ __forceinline__ void stage_tile(const char* gtile, char* ltile,
                                           int wave, int lane) {
    const char* g = gtile + wave * 4096 + lane * 16;
    char* l = ltile + wave * 4096;
#pragma unroll
    for (int i = 0; i < 4; ++i)
        __builtin_amdgcn_global_load_lds((as1cv)(g + i * 1024),
                                         (as3v)(l + i * 1024), 16, 0, 0);
}

// ---------------------------------------------------------------------------
// Kernel 1: column sums of H2 (H1's sums come fused from its score pass).
__global__ __launch_bounds__(256) void k_mean2(const float* __restrict__ H2,
                                               float* __restrict__ hsum) {
    __shared__ float buf[2][TROWS * DD];   // 2 x 16 KB
    __shared__ float4 cred[4][32];
    int tid = threadIdx.x;
    int wave = tid >> 6, lane = tid & 63;
    int batch = blockIdx.x >> 6, sub = blockIdx.x & 63;
    const char* Hbase = (const char*)(H2 + ((size_t)batch * NN + (size_t)sub * RPB) * DD);
    int g = tid >> 4;        // 0..15: rows g and g+16 of each tile
    int c0 = tid & 15;       // f4 cols c0 and c0+16

    float4 cs0 = make_float4(0.f, 0.f, 0.f, 0.f), cs1 = cs0;

    stage_tile(Hbase, (char*)buf[0], wave, lane);
    __syncthreads();     // compiler drains vmcnt before barrier -> tile 0 ready
    for (int t = 0; t < NTILES; ++t) {
        if (t + 1 < NTILES)
            stage_tile(Hbase + (size_t)(t + 1) * TBYTES, (char*)buf[(t + 1) & 1], wave, lane);
        const float* B = buf[t & 1];
#pragma unroll
        for (int half = 0; half < 2; ++half) {
            int r = g + half * 16;
            float4 h0 = *(const float4*)(B + r * DD + c0 * 4);
            float4 h1 = *(const float4*)(B + r * DD + 64 + c0 * 4);
            cs0.x += h0.x; cs0.y += h0.y; cs0.z += h0.z; cs0.w += h0.w;
            cs1.x += h1.x; cs1.y += h1.y; cs1.z += h1.z; cs1.w += h1.w;
        }
        __syncthreads();  // buf[t] consumed; tile t+1 landed
    }
    // lanes sharing c0 (l, l+16, l+32, l+48) cover same columns -> reduce rows
    cs0.x += __shfl_xor(cs0.x, 16); cs0.x += __shfl_xor(cs0.x, 32);
    cs0.y += __shfl_xor(cs0.y, 16); cs0.y += __shfl_xor(cs0.y, 32);
    cs0.z += __shfl_xor(cs0.z, 16); cs0.z += __shfl_xor(cs0.z, 32);
    cs0.w += __shfl_xor(cs0.w, 16); cs0.w += __shfl_xor(cs0.w, 32);
    cs1.x += __shfl_xor(cs1.x, 16); cs1.x += __shfl_xor(cs1.x, 32);
    cs1.y += __shfl_xor(cs1.y, 16); cs1.y += __shfl_xor(cs1.y, 32);
    cs1.z += __shfl_xor(cs1.z, 16); cs1.z += __shfl_xor(cs1.z, 32);
    cs1.w += __shfl_xor(cs1.w, 16); cs1.w += __shfl_xor(cs1.w, 32);
    if (lane < 16) {
        cred[wave][lane] = cs0;
        cred[wave][lane + 16] = cs1;
    }
    __syncthreads();
    if (tid < 32) {
        float4 s0 = cred[0][tid], s1 = cred[1][tid], s2 = cred[2][tid], s3 = cred[3][tid];
        float* dst = hsum + (size_t)(NB + batch) * DD + tid * 4;
        atomicAdd(dst + 0, s0.x + s1.x + s2.x + s3.x);
        atomicAdd(dst + 1, s0.y + s1.y + s2.y + s3.y);
        atomicAdd(dst + 2, s0.z + s1.z + s2.z + s3.z);
        atomicAdd(dst + 3, s0.w + s1.w + s2.w + s3.w);
    }
}

// ---------------------------------------------------------------------------
// Kernel 2: v[p][b][k][d] = scale * sum_e W[k][d][e] * hsum[1-p][b][e]
__global__ __launch_bounds__(128) void k_v(const float* __restrict__ W1,
                                           const float* __restrict__ W2,
                                           const float* __restrict__ hsum,
                                           float* __restrict__ v, int p) {
    int bi = blockIdx.x;
    int b = bi / 10;
    int k = bi % 10;
    const float* W = (p ? W2 : W1) + (size_t)k * DD * DD;
    const float* hb = hsum + (size_t)((1 - p) * NB + b) * DD;
    __shared__ float4 h_s[32];
    int tid = threadIdx.x;
    if (tid < 32) h_s[tid] = ((const float4*)hb)[tid];
    __syncthreads();
    const float4* Wrow = (const float4*)(W + (size_t)tid * DD);
    float acc = 0.f;
#pragma unroll 8
    for (int e4 = 0; e4 < 32; ++e4) {
        float4 w4 = Wrow[e4];
        float4 h4 = h_s[e4];
        acc += w4.x * h4.x + w4.y * h4.y + w4.z * h4.z + w4.w * h4.w;
    }
    const float SCALE = (float)(1.0 / (16384.0 * 11.313708498984761));  // 1/(N*sqrt(128))
    v[((size_t)(p * NB + b) * KK + k) * DD + tid] = acc * SCALE;
}

// ---------------------------------------------------------------------------
// Kernel 3: score pass (exp-scores + weighted-X sums; optional fused col-sums).
// H staged tile-by-tile via global_load_lds; v held in registers (20 f4).
__global__ __launch_bounds__(256) void k_pass(const float* __restrict__ H,
                                              const float* __restrict__ X,
                                              const float* __restrict__ v,
                                              float* __restrict__ accg,
                                              float* __restrict__ hsumout,
                                              int do_sum) {
    __shared__ float buf[2][TROWS * DD];   // 2 x 16 KB
    __shared__ float red[4][40];
    __shared__ float4 cred[4][32];
    int tid = threadIdx.x;
    int wave = tid >> 6, lane = tid & 63;
    int batch = blockIdx.x >> 6, sub = blockIdx.x & 63;
    int row0 = sub * RPB;
    const char* Hbase = (const char*)(H + ((size_t)batch * NN + (size_t)row0) * DD);
    const float* Xb = X + (size_t)batch * NN * 3;
    const float4* v4 = (const float4*)(v + (size_t)batch * KK * DD);
    int g = tid >> 4;        // 0..15: rows g and g+16 of each tile
    int c0 = tid & 15;       // f4 cols c0 and c0+16

    float4 va[KK], vb[KK];
#pragma unroll
    for (int k = 0; k < KK; ++k) {
        va[k] = v4[k * 32 + c0];
        vb[k] = v4[k * 32 + c0 + 16];
    }

    float pSE[KK], pY0[KK], pY1[KK], pY2[KK];
#pragma unroll
    for (int k = 0; k < KK; ++k) { pSE[k] = 0.f; pY0[k] = 0.f; pY1[k] = 0.f; pY2[k] = 0.f; }
    float4 cs0 = make_float4(0.f, 0.f, 0.f, 0.f), cs1 = cs0;

    stage_tile(Hbase, (char*)buf[0], wave, lane);
    __syncthreads();     // tile 0 ready
    for (int t = 0; t < NTILES; ++t) {
        if (t + 1 < NTILES)
            stage_tile(Hbase + (size_t)(t + 1) * TBYTES, (char*)buf[(t + 1) & 1], wave, lane);
        const float* B = buf[t & 1];
#pragma unroll
        for (int half = 0; half < 2; ++half) {
            int r = g + half * 16;
            float4 h0 = *(const float4*)(B + r * DD + c0 * 4);
            float4 h1 = *(const float4*)(B + r * DD + 64 + c0 * 4);
            int rowg = row0 + t * TROWS + r;
            float x0 = Xb[rowg * 3 + 0], x1 = Xb[rowg * 3 + 1], x2 = Xb[rowg * 3 + 2];
            float sc[KK];
#pragma unroll
            for (int k = 0; k < KK; ++k)
                sc[k] = h0.x * va[k].x + h0.y * va[k].y + h0.z * va[k].z + h0.w * va[k].w
                      + h1.x * vb[k].x + h1.y * vb[k].y + h1.z * vb[k].z + h1.w * vb[k].w;
            // reduce 128-dot across the 16 lanes of the row
#pragma unroll
            for (int k = 0; k < KK; ++k) {
                sc[k] += __shfl_xor(sc[k], 1);
                sc[k] += __shfl_xor(sc[k], 2);
                sc[k] += __shfl_xor(sc[k], 4);
                sc[k] += __shfl_xor(sc[k], 8);
            }
            // |s| <~ 0.3 -> exp without max-subtraction is exact softmax.
            if (c0 == 0) {
#pragma unroll
                for (int k = 0; k < KK; ++k) {
                    float e = __expf(sc[k]);
                    pSE[k] += e;
                    pY0[k] += e * x0;
                    pY1[k] += e * x1;
                    pY2[k] += e * x2;
                }
            }
            if (do_sum) {
                cs0.x += h0.x; cs0.y += h0.y; cs0.z += h0.z; cs0.w += h0.w;
                cs1.x += h1.x; cs1.y += h1.y; cs1.z += h1.z; cs1.w += h1.w;
            }
        }
        __syncthreads();  // buf[t] consumed; tile t+1 landed
    }

    // pSE/pY live on lanes 0,16,32,48 -> sum the 4 row-groups of the wave
#pragma unroll
    for (int k = 0; k < KK; ++k) {
        pSE[k] += __shfl_xor(pSE[k], 16); pSE[k] += __shfl_xor(pSE[k], 32);
        pY0[k] += __shfl_xor(pY0[k], 16); pY0[k] += __shfl_xor(pY0[k], 32);
        pY1[k] += __shfl_xor(pY1[k], 16); pY1[k] += __shfl_xor(pY1[k], 32);
        pY2[k] += __shfl_xor(pY2[k], 16); pY2[k] += __shfl_xor(pY2[k], 32);
    }
    if (lane == 0) {
#pragma unroll
        for (int k = 0; k < KK; ++k) {
            red[wave][k] = pSE[k];
            red[wave][10 + k] = pY0[k];
            red[wave][20 + k] = pY1[k];
            red[wave][30 + k] = pY2[k];
        }
    }
    if (do_sum) {
        cs0.x += __shfl_xor(cs0.x, 16); cs0.x += __shfl_xor(cs0.x, 32);
        cs0.y += __shfl_xor(cs0.y, 16); cs0.y += __shfl_xor(cs0.y, 32);
        cs0.z += __shfl_xor(cs0.z, 16); cs0.z += __shfl_xor(cs0.z, 32);
        cs0.w += __shfl_xor(cs0.w, 16); cs0.w += __shfl_xor(cs0.w, 32);
        cs1.x += __shfl_xor(cs1.x, 16); cs1.x += __shfl_xor(cs1.x, 32);
        cs1.y += __shfl_xor(cs1.y, 16); cs1.y += __shfl_xor(cs1.y, 32);
        cs1.z += __shfl_xor(cs1.z, 16); cs1.z += __shfl_xor(cs1.z, 32);
        cs1.w += __shfl_xor(cs1.w, 16); cs1.w += __shfl_xor(cs1.w, 32);
        if (lane < 16) {
            cred[wave][lane] = cs0;
            cred[wave][lane + 16] = cs1;
        }
    }
    __syncthreads();
    if (tid < 40) {
        float ssum = red[0][tid] + red[1][tid] + red[2][tid] + red[3][tid];
        atomicAdd(accg + (size_t)batch * 40 + tid, ssum);
    }
    if (do_sum && tid >= 64 && tid < 96) {
        int c = tid - 64;  // f4 column 0..31
        float4 s0 = cred[0][c], s1 = cred[1][c], s2 = cred[2][c], s3 = cred[3][c];
        float* dst = hsumout + (size_t)batch * DD + c * 4;
        atomicAdd(dst + 0, s0.x + s1.x + s2.x + s3.x);
        atomicAdd(dst + 1, s0.y + s1.y + s2.y + s3.y);
        atomicAdd(dst + 2, s0.z + s1.z + s2.z + s3.z);
        atomicAdd(dst + 3, s0.w + s1.w + s2.w + s3.w);
    }
}

// ---------------------------------------------------------------------------
// Kernel 4: finalize Y1/Y2 and Kabsch alignment (fp64 one-sided Jacobi SVD).
__global__ __launch_bounds__(64) void k_final(const float* __restrict__ accg,
                                              float* __restrict__ out) {
    int b = blockIdx.x;
    int tid = threadIdx.x;
    __shared__ float Ys[2][KK][3];
    if (tid < 2 * KK * 3) {
        int p = tid / 30;
        int r = tid % 30;
        int k = r / 3;
        int c = r % 3;
        const float* a = accg + (size_t)(p * NB + b) * 40;
        float val = a[10 + c * 10 + k] / a[k];
        Ys[p][k][c] = val;
        out[((size_t)(b * 3 + p) * KK + k) * 3 + c] = val;
    }
    __syncthreads();
    if (tid == 0) {
        double P[KK][3], Q[KK][3];
        double c1[3] = {0, 0, 0}, c2[3] = {0, 0, 0};
        for (int i = 0; i < KK; ++i)
            for (int c = 0; c < 3; ++c) {
                P[i][c] = (double)Ys[0][i][c];
                Q[i][c] = (double)Ys[1][i][c];
                c1[c] += P[i][c];
                c2[c] += Q[i][c];
            }
        for (int c = 0; c < 3; ++c) { c1[c] /= KK; c2[c] /= KK; }
        double A0[3][3];
        for (int a = 0; a < 3; ++a)
            for (int c = 0; c < 3; ++c) {
                double s = 0;
                for (int i = 0; i < KK; ++i) s += (P[i][a] - c1[a]) * (Q[i][c] - c2[c]);
                A0[a][c] = s;
            }
        double Bm[3][3], V[3][3];
        for (int a = 0; a < 3; ++a)
            for (int c = 0; c < 3; ++c) { Bm[a][c] = A0[a][c]; V[a][c] = (a == c) ? 1.0 : 0.0; }
        for (int sweep = 0; sweep < 16; ++sweep)
            for (int p = 0; p < 2; ++p)
                for (int q = p + 1; q < 3; ++q) {
                    double al = 0, be = 0, ga = 0;
                    for (int r = 0; r < 3; ++r) {
                        al += Bm[r][p] * Bm[r][p];
                        be += Bm[r][q] * Bm[r][q];
                        ga += Bm[r][p] * Bm[r][q];
                    }
                    if (fabs(ga) < 1e-300) continue;
                    double zeta = (be - al) / (2.0 * ga);
                    double t = copysign(1.0, zeta) / (fabs(zeta) + sqrt(1.0 + zeta * zeta));
                    double cs = 1.0 / sqrt(1.0 + t * t);
                    double sn = cs * t;
                    for (int r = 0; r < 3; ++r) {
                        double bp = Bm[r][p], bq = Bm[r][q];
                        Bm[r][p] = cs * bp - sn * bq;
                        Bm[r][q] = sn * bp + cs * bq;
                        double vp = V[r][p], vq = V[r][q];
                        V[r][p] = cs * vp - sn * vq;
                        V[r][q] = sn * vp + cs * vq;
                    }
                }
        double sig[3];
        for (int j = 0; j < 3; ++j) {
            sig[j] = sqrt(Bm[0][j] * Bm[0][j] + Bm[1][j] * Bm[1][j] + Bm[2][j] * Bm[2][j]);
            if (sig[j] < 1e-300) sig[j] = 1e-300;
        }
        int jmin = 0;
        if (sig[1] < sig[jmin]) jmin = 1;
        if (sig[2] < sig[jmin]) jmin = 2;
        double det = A0[0][0] * (A0[1][1] * A0[2][2] - A0[1][2] * A0[2][1])
                   - A0[0][1] * (A0[1][0] * A0[2][2] - A0[1][2] * A0[2][0])
                   + A0[0][2] * (A0[1][0] * A0[2][1] - A0[1][1] * A0[2][0]);
        double sgn = (det >= 0.0) ? 1.0 : -1.0;
        double R[3][3];
        for (int a = 0; a < 3; ++a)
            for (int c = 0; c < 3; ++c) {
                double s = 0;
                for (int j = 0; j < 3; ++j) {
                    double dj = (j == jmin) ? sgn : 1.0;
                    s += dj * (Bm[a][j] / sig[j]) * V[c][j];
                }
                R[a][c] = s;
            }
        for (int i = 0; i < KK; ++i)
            for (int c = 0; c < 3; ++c) {
                double s = c2[c];
                for (int a = 0; a < 3; ++a) s += (P[i][a] - c1[a]) * R[a][c];
                out[((size_t)(b * 3 + 2) * KK + i) * 3 + c] = (float)s;
            }
    }
}

// ---------------------------------------------------------------------------
extern "C" void kernel_launch(void* const* d_in, const int* in_sizes, int n_in,
                              void* d_out, int out_size, void* d_ws, size_t ws_size,
                              hipStream_t stream) {
    const float* H1 = (const float*)d_in[0];
    const float* H2 = (const float*)d_in[1];
    const float* X1 = (const float*)d_in[2];
    const float* X2 = (const float*)d_in[3];
    const float* W1 = (const float*)d_in[4];
    const float* W2 = (const float*)d_in[5];
    float* out = (float*)d_out;
    float* ws = (float*)d_ws;
    float* hsum = ws;              // 4096 floats
    float* v    = ws + 4096;       // 40960 floats
    float* accg = ws + 45056;      // 1280 floats

    hipMemsetAsync(d_ws, 0, WS_FLOATS * sizeof(float), stream);
    // Sweep 1: H2 column sums
    hipLaunchKernelGGL(k_mean2, dim3(1024), dim3(256), 0, stream, H2, hsum);
    hipLaunchKernelGGL(k_v, dim3(160), dim3(128), 0, stream, W1, W2, hsum, v, 0);
    // Sweep 2: H1 scores + fused H1 column sums
    hipLaunchKernelGGL(k_pass, dim3(1024), dim3(256), 0, stream,
                       H1, X1, v, accg, hsum, 1);
    hipLaunchKernelGGL(k_v, dim3(160), dim3(128), 0, stream, W1, W2, hsum, v, 1);
    // Sweep 3: H2 scores
    hipLaunchKernelGGL(k_pass, dim3(1024), dim3(256), 0, stream,
                       H2, X2, v + (size_t)NB * KK * DD, accg + (size_t)NB * 40, hsum, 0);
    hipLaunchKernelGGL(k_final, dim3(16), dim3(64), 0, stream, accg, out);
}